// Round 7
// baseline (4588.831 us; speedup 1.0000x reference)
//
#include <hip/hip_runtime.h>

// GRU: T=1024, B=256, I=H=O=256, fp32 in/out, bf16 MFMA internally.
// d_out layout: outs [T*B][O] fp32 then h_final [B][H] fp32.
// xr_p/xz_p (bf16 packed, 134MB each) live in the d_out outs region and are
// fully consumed by gru_scan before gru_out overwrites it. xh_p lives in d_ws
// and is overwritten in-place by cand during the scan.
// R1: LDS-only barriers (no vmcnt drain).
// R2: VALU diet (v_rcp, v_cvt_pk_bf16_f32, MFMA C-in seeded with x-preacts).
// R4: whr+whh register/AGPR-resident (PINned); whz streamed via 2-deep dbuf.
// R5 (FAILED, reverted): paired-nb layout + asm exp activations bundled; 28.9
//     absmax. Bisecting:
// R6 = R4 + log2e folding ONLY (activations via __builtin_amdgcn_exp2f/rcpf,
//     weights/biases/x-preacts pre-scaled: sigma(x)=rcp(1+2^-y), y=L2E*x;
//     tanh(x)=1-2*rcp(2^y+1), y=2*L2E*x) + setprio. Old x layout kept.

typedef unsigned short u16t;
typedef unsigned int   u32t;
typedef short  s16x8 __attribute__((ext_vector_type(8)));
typedef float  f32x4 __attribute__((ext_vector_type(4)));
typedef float  f32v4 __attribute__((ext_vector_type(4)));
typedef u32t   u32x2 __attribute__((ext_vector_type(2)));

#define GBYTES 134217728ull   // T*B*H * 2 bytes (one packed gate)
#define L2E 1.4426950408889634f

// LDS-only barrier: order ds ops, leave vmcnt in flight.
#define BAR_LDS() asm volatile("s_waitcnt lgkmcnt(0)\n\ts_barrier" ::: "memory")
// Pin a value in VGPRs/AGPRs: opaque to the optimizer, no remat.
#define PIN(v) asm volatile("" : "+v"(v))

__device__ __forceinline__ float lo_f(u32t u) {
  return __builtin_bit_cast(float, u << 16);
}
__device__ __forceinline__ float hi_f(u32t u) {
  return __builtin_bit_cast(float, u & 0xffff0000u);
}
__device__ __forceinline__ u32t f2bf(float f) {  // round-to-nearest-even
  u32t u = __builtin_bit_cast(u32t, f);
  return (u + 0x7fffu + ((u >> 16) & 1u)) >> 16;
}
__device__ __forceinline__ u32t cvtpk(float lo, float hi) {  // 2xbf16 RNE pack
  u32t r;
  asm("v_cvt_pk_bf16_f32 %0, %1, %2" : "=v"(r) : "v"(lo), "v"(hi));
  return r;
}
__device__ __forceinline__ f32x4 MF(s16x8 a, s16x8 b, f32x4 c) {
  return __builtin_amdgcn_mfma_f32_16x16x32_bf16(a, b, c, 0, 0, 0);
}
// y = x*log2e already folded into operands: sigma(x) = 1/(1+2^-y)
__device__ __forceinline__ float sigm2(float y) {
  return __builtin_amdgcn_rcpf(1.0f + __builtin_amdgcn_exp2f(-y));
}
// y = x*2*log2e folded: tanh(x) = 1 - 2/(2^y + 1)
__device__ __forceinline__ float tanh2(float y) {
  return fmaf(-2.0f, __builtin_amdgcn_rcpf(__builtin_amdgcn_exp2f(y) + 1.0f), 1.0f);
}

// ---------------------------------------------------------------------------
// Pack 7 weight matrices [256x256] fp32 row-major -> bf16 MFMA-B fragments,
// pre-scaled: wxr,wxz,whr,whz by log2e; wxh,whh by 2*log2e; wout by 1.
// Fragment (nb, ks): lane holds W[ks*32 + (lane>>4)*8 + j][nb*16 + (lane&15)],
// stored at element ((nb*8+ks)*64 + lane)*8 + j.
// Order: [wxr, wxz, wxh, whr, whz, whh, wout] at 65536-elem strides.
// ---------------------------------------------------------------------------
__global__ void pack_w(const float* __restrict__ wxr, const float* __restrict__ wxz,
                       const float* __restrict__ wxh, const float* __restrict__ whr,
                       const float* __restrict__ whz, const float* __restrict__ whh,
                       const float* __restrict__ wout, u16t* __restrict__ dst) {
  int e = blockIdx.x * 256 + threadIdx.x;     // [0, 7*65536)
  int mat = e >> 16, i = e & 65535;
  const float* src = mat == 0 ? wxr : mat == 1 ? wxz : mat == 2 ? wxh
                   : mat == 3 ? whr : mat == 4 ? whz : mat == 5 ? whh : wout;
  float sc = (mat == 2 || mat == 5) ? 2.0f * L2E : (mat == 6 ? 1.0f : L2E);
  int j = i & 7, lane = (i >> 3) & 63, ks = (i >> 9) & 7, nb = i >> 12;
  int k = ks * 32 + (lane >> 4) * 8 + j;
  int n = nb * 16 + (lane & 15);
  dst[e] = (u16t)f2bf(src[k * 256 + n] * sc);
}

// ---------------------------------------------------------------------------
// Phase 1: xg = x @ Wxg + bg (pre-scaled), written bf16 in C-frag-packed
// layout: gate_p[((t*16+wg)*16+nb)*64+lane] (u32x2 = 4 bf16 regs).
// ---------------------------------------------------------------------------
__global__ __launch_bounds__(512, 2) void gru_xproj(
    const float* __restrict__ x, const u16t* __restrict__ wpack,
    const float* __restrict__ br, const float* __restrict__ bz,
    const float* __restrict__ bh,
    u16t* __restrict__ xr_p, u16t* __restrict__ xz_p, u16t* __restrict__ xh_p) {
  __shared__ __align__(128) u16t xt[16384];   // [64][256] bf16, XOR-swizzled
  const int tid = threadIdx.x, bid = blockIdx.x;
  const int t = bid >> 2, b0 = (bid & 3) * 64;
  const float* xrow = x + ((size_t)t * 256 + b0) * 256;
#pragma unroll
  for (int c = 0; c < 8; ++c) {
    int f4 = c * 512 + tid;                   // [0,4096) float4s
    f32v4 v = ((const f32v4*)xrow)[f4];
    u32t lo = f2bf(v[0]) | (f2bf(v[1]) << 16);
    u32t hi = f2bf(v[2]) | (f2bf(v[3]) << 16);
    int row = f4 >> 6, c8 = (f4 & 63) * 8;
    int off = (row * 512 + c8) ^ ((row & 7) << 4);
    u32x2 vv; vv[0] = lo; vv[1] = hi;
    *(u32x2*)((char*)xt + off) = vv;
  }
  __syncthreads();
  const int lane = tid & 63, w = tid >> 6;
  const int mt = w & 3, half = w >> 2;
  const int arow = mt * 16 + (lane & 15);
  const int abase = arow * 512 + (lane >> 4) * 16;
  const int asw = (lane & 7) << 4;
  const f32x4 Z = {0.f, 0.f, 0.f, 0.f};
  f32x4 acc[24];
#pragma unroll
  for (int p = 0; p < 24; ++p) acc[p] = Z;
#pragma unroll
  for (int ks = 0; ks < 8; ++ks) {
    s16x8 a = *(const s16x8*)((char*)xt + ((abase + ks * 64) ^ asw));
#pragma unroll
    for (int p = 0; p < 24; ++p) {
      int pj = half * 24 + p;
      int gate = pj >> 4, nb = pj & 15;
      const s16x8* wb = (const s16x8*)wpack + gate * 8192;
      acc[p] = MF(a, wb[(nb * 8 + ks) * 64 + lane], acc[p]);
    }
  }
  const int wg = (b0 >> 4) + mt;
#pragma unroll
  for (int p = 0; p < 24; ++p) {
    int pj = half * 24 + p;
    int gate = pj >> 4, nb = pj & 15;
    const float* bp = gate == 0 ? br : gate == 1 ? bz : bh;
    float bs = (gate == 2) ? 2.0f * L2E : L2E;
    float bv = bp[nb * 16 + (lane & 15)] * bs;
    u32t lo = f2bf(acc[p][0] + bv) | (f2bf(acc[p][1] + bv) << 16);
    u32t hi = f2bf(acc[p][2] + bv) | (f2bf(acc[p][3] + bv) << 16);
    u16t* op = gate == 0 ? xr_p : gate == 1 ? xz_p : xh_p;
    size_t off = (((size_t)t * 16 + wg) * 16 + nb) * 64 + lane;
    u32x2 vv; vv[0] = lo; vv[1] = hi;
    ((u32x2*)op)[off] = vv;
  }
}

// ---------------------------------------------------------------------------
// Phase 2: sequential scan. 16 WGs x 512 thr (8 waves; wave w owns cols
// [w*32, w*32+32) = nb {2w, 2w+1}). h fp32 in registers (C-frag layout);
// bf16 h / r*h through XOR-swizzled LDS as A-fragments.
// whr + whh AGPR-resident (pinned); whz streamed from L2 via dbuf.
// ---------------------------------------------------------------------------
#define OFFSW(row, colx2) (((row) * 512 + (colx2)) ^ (((row) & 7) << 4))
#define LDA_HB(ks) (*(const s16x8*)((char*)hb + ((aoff + (ks) * 64) ^ asw)))
#define LDA_RH(ks) (*(const s16x8*)((char*)rh + ((aoff + (ks) * 64) ^ asw)))
#define ZLOAD(buf, ks) do { buf[0] = pz[(ks) * 64]; buf[1] = pz[(ks) * 64 + 512]; } while (0)
#define G1_STEP(buf, ks) do { s16x8 a_ = LDA_HB(ks); \
    ar0 = MF(a_, whr_r[0][ks], ar0); ar1 = MF(a_, whr_r[1][ks], ar1); \
    az0 = MF(a_, buf[0], az0);       az1 = MF(a_, buf[1], az1); } while (0)

__global__ __launch_bounds__(512, 2) void gru_scan(
    const float* __restrict__ h0, const u16t* __restrict__ wpack,
    const u16t* __restrict__ xr_p, const u16t* __restrict__ xz_p,
    const u16t* __restrict__ xh_p, u16t* __restrict__ cand_p,
    float* __restrict__ hout) {
  __shared__ __align__(128) u16t hb[4096];    // [16][256] bf16 swizzled
  __shared__ __align__(128) u16t rh[4096];
  const int tid = threadIdx.x, lane = tid & 63, w = tid >> 6;
  const int wg = blockIdx.x;
  const int rlo = (lane >> 4) * 4;            // local row base (0,4,8,12)
  const int cA = w * 32 + (lane & 15);        // column for c=0 (c=1 -> +16)

  float hr_[2][4];
#pragma unroll
  for (int c = 0; c < 2; ++c)
#pragma unroll
    for (int j = 0; j < 4; ++j)
      hr_[c][j] = h0[(size_t)(wg * 16 + rlo + j) * 256 + cA + c * 16];
#pragma unroll
  for (int c = 0; c < 2; ++c)
#pragma unroll
    for (int j = 0; j < 4; ++j)
      *(u16t*)((char*)hb + OFFSW(rlo + j, (cA + c * 16) * 2)) = (u16t)f2bf(hr_[c][j]);
  __syncthreads();

  const s16x8* pz = (const s16x8*)wpack + 4 * 8192 + w * 1024 + lane;
  const int aoff = (lane & 15) * 512 + (lane >> 4) * 16;
  const int asw = (lane & 7) << 4;

  // whr / whh resident (pinned; allocator uses AGPRs, zero in-loop cost).
  s16x8 whr_r[2][8], whh_r[2][8];
  {
    const s16x8* prw = (const s16x8*)wpack + 3 * 8192;
    const s16x8* phw = (const s16x8*)wpack + 5 * 8192;
#pragma unroll
    for (int c = 0; c < 2; ++c)
#pragma unroll
      for (int ks = 0; ks < 8; ++ks) {
        int fo = ((2 * w + c) * 8 + ks) * 64 + lane;
        whr_r[c][ks] = prw[fo]; PIN(whr_r[c][ks]);
        whh_r[c][ks] = phw[fo]; PIN(whh_r[c][ks]);
      }
  }

  const size_t xoff = (size_t)(wg * 16 + 2 * w) * 64 + lane;  // u32x2 units
  const u32x2* PXR = (const u32x2*)xr_p;
  const u32x2* PXZ = (const u32x2*)xz_p;
  const u32x2* PXH = (const u32x2*)xh_p;
  u32x2* SXH = (u32x2*)cand_p;

  u32x2 vxr0 = PXR[xoff], vxr1 = PXR[xoff + 64];
  u32x2 vxz0 = PXZ[xoff], vxz1 = PXZ[xoff + 64];
  u32x2 vxh0 = PXH[xoff], vxh1 = PXH[xoff + 64];

  s16x8 bA[2], bB[2];
  ZLOAD(bA, 0);
  ZLOAD(bB, 1);

  for (int t = 0; t < 1024; ++t) {
    // G1: accs seeded with x-preacts; whz dbuf-streamed; whr from regs.
    f32x4 ar0, ar1, az0, az1;
    ar0[0] = lo_f(vxr0[0]); ar0[1] = hi_f(vxr0[0]); ar0[2] = lo_f(vxr0[1]); ar0[3] = hi_f(vxr0[1]);
    ar1[0] = lo_f(vxr1[0]); ar1[1] = hi_f(vxr1[0]); ar1[2] = lo_f(vxr1[1]); ar1[3] = hi_f(vxr1[1]);
    az0[0] = lo_f(vxz0[0]); az0[1] = hi_f(vxz0[0]); az0[2] = lo_f(vxz0[1]); az0[3] = hi_f(vxz0[1]);
    az1[0] = lo_f(vxz1[0]); az1[1] = hi_f(vxz1[0]); az1[2] = lo_f(vxz1[1]); az1[3] = hi_f(vxz1[1]);

    __builtin_amdgcn_s_setprio(1);
    G1_STEP(bA, 0); ZLOAD(bA, 2);
    G1_STEP(bB, 1); ZLOAD(bB, 3);
    G1_STEP(bA, 2); ZLOAD(bA, 4);
    G1_STEP(bB, 3); ZLOAD(bB, 5);
    G1_STEP(bA, 4); ZLOAD(bA, 6);
    G1_STEP(bB, 5); ZLOAD(bB, 7);
    G1_STEP(bA, 6);
    G1_STEP(bB, 7);
    __builtin_amdgcn_s_setprio(0);

    float r_[2][4];
    r_[0][0] = sigm2(ar0[0]); r_[0][1] = sigm2(ar0[1]); r_[0][2] = sigm2(ar0[2]); r_[0][3] = sigm2(ar0[3]);
    r_[1][0] = sigm2(ar1[0]); r_[1][1] = sigm2(ar1[1]); r_[1][2] = sigm2(ar1[2]); r_[1][3] = sigm2(ar1[3]);

#pragma unroll
    for (int c = 0; c < 2; ++c) {
      u32t p01 = cvtpk(r_[c][0] * hr_[c][0], r_[c][1] * hr_[c][1]);
      u32t p23 = cvtpk(r_[c][2] * hr_[c][2], r_[c][3] * hr_[c][3]);
      *(u16t*)((char*)rh + OFFSW(rlo + 0, (cA + c * 16) * 2)) = (u16t)p01;
      *(u16t*)((char*)rh + OFFSW(rlo + 1, (cA + c * 16) * 2)) = (u16t)(p01 >> 16);
      *(u16t*)((char*)rh + OFFSW(rlo + 2, (cA + c * 16) * 2)) = (u16t)p23;
      *(u16t*)((char*)rh + OFFSW(rlo + 3, (cA + c * 16) * 2)) = (u16t)(p23 >> 16);
    }
    BAR_LDS();

    // barrier shadow: z-sigmoid + G2 seeding + x reload for t+1
    float z_[2][4];
    z_[0][0] = sigm2(az0[0]); z_[0][1] = sigm2(az0[1]); z_[0][2] = sigm2(az0[2]); z_[0][3] = sigm2(az0[3]);
    z_[1][0] = sigm2(az1[0]); z_[1][1] = sigm2(az1[1]); z_[1][2] = sigm2(az1[2]); z_[1][3] = sigm2(az1[3]);

    f32x4 ac0, ac1;
    ac0[0] = lo_f(vxh0[0]); ac0[1] = hi_f(vxh0[0]); ac0[2] = lo_f(vxh0[1]); ac0[3] = hi_f(vxh0[1]);
    ac1[0] = lo_f(vxh1[0]); ac1[1] = hi_f(vxh1[0]); ac1[2] = lo_f(vxh1[1]); ac1[3] = hi_f(vxh1[1]);

    {  // reload x regs for t+1 (consumed above; arrival needed next step)
      size_t onext = xoff + (size_t)(t < 1023 ? t + 1 : t) * 16384;
      vxr0 = PXR[onext]; vxr1 = PXR[onext + 64];
      vxz0 = PXZ[onext]; vxz1 = PXZ[onext + 64];
      vxh0 = PXH[onext]; vxh1 = PXH[onext + 64];
    }

    // G2: (r.h) @ Whh with register-resident B
    __builtin_amdgcn_s_setprio(1);
#pragma unroll
    for (int ks = 0; ks < 8; ++ks) {
      s16x8 a_ = LDA_RH(ks);
      ac0 = MF(a_, whh_r[0][ks], ac0);
      ac1 = MF(a_, whh_r[1][ks], ac1);
    }
    __builtin_amdgcn_s_setprio(0);

    float cd[2][4];
    cd[0][0] = tanh2(ac0[0]); cd[0][1] = tanh2(ac0[1]); cd[0][2] = tanh2(ac0[2]); cd[0][3] = tanh2(ac0[3]);
    cd[1][0] = tanh2(ac1[0]); cd[1][1] = tanh2(ac1[1]); cd[1][2] = tanh2(ac1[2]); cd[1][3] = tanh2(ac1[3]);

    // store cand (bf16) over xh_p[t] via cand_p
    size_t ocur = xoff + (size_t)t * 16384;
    u32x2 s0, s1;
    s0[0] = cvtpk(cd[0][0], cd[0][1]); s0[1] = cvtpk(cd[0][2], cd[0][3]);
    s1[0] = cvtpk(cd[1][0], cd[1][1]); s1[1] = cvtpk(cd[1][2], cd[1][3]);
    SXH[ocur] = s0;
    SXH[ocur + 64] = s1;

    // h update + hb refresh
#pragma unroll
    for (int c = 0; c < 2; ++c) {
#pragma unroll
      for (int j = 0; j < 4; ++j)
        hr_[c][j] = fmaf(z_[c][j], hr_[c][j] - cd[c][j], cd[c][j]);
      u32t p01 = cvtpk(hr_[c][0], hr_[c][1]);
      u32t p23 = cvtpk(hr_[c][2], hr_[c][3]);
      *(u16t*)((char*)hb + OFFSW(rlo + 0, (cA + c * 16) * 2)) = (u16t)p01;
      *(u16t*)((char*)hb + OFFSW(rlo + 1, (cA + c * 16) * 2)) = (u16t)(p01 >> 16);
      *(u16t*)((char*)hb + OFFSW(rlo + 2, (cA + c * 16) * 2)) = (u16t)p23;
      *(u16t*)((char*)hb + OFFSW(rlo + 3, (cA + c * 16) * 2)) = (u16t)(p23 >> 16);
    }

    // cross-barrier preload of next step's first whz frags
    ZLOAD(bA, 0);
    ZLOAD(bB, 1);
    BAR_LDS();
  }
#pragma unroll
  for (int c = 0; c < 2; ++c)
#pragma unroll
    for (int j = 0; j < 4; ++j)
      hout[(size_t)(wg * 16 + rlo + j) * 256 + cA + c * 16] = hr_[c][j];
}

// ---------------------------------------------------------------------------
// Phase 3: outs = cand @ Wout + bout (fp32 out).
// ---------------------------------------------------------------------------
__global__ __launch_bounds__(1024, 4) void gru_out(
    const u16t* __restrict__ cand_p, const u16t* __restrict__ wpack,
    const float* __restrict__ bout, float* __restrict__ out) {
  __shared__ __align__(128) u16t cm[16384];   // [64][256] bf16 swizzled
  const int tid = threadIdx.x, bid = blockIdx.x;
  const int t = bid >> 2, q = bid & 3, b0 = q * 64;
  const u32x2* src = (const u32x2*)cand_p + ((size_t)t * 16 + q * 4) * 1024;
#pragma unroll
  for (int it = 0; it < 4; ++it) {
    int i = it * 1024 + tid;
    u32x2 v = src[i];
    int wg_l = i >> 10, nb = (i >> 6) & 15, ls = i & 63;
    int brow = wg_l * 16 + (ls >> 4) * 4;
    int hc2 = (nb * 16 + (ls & 15)) * 2;
    u16t ev[4] = {(u16t)(v[0] & 0xffff), (u16t)(v[0] >> 16),
                  (u16t)(v[1] & 0xffff), (u16t)(v[1] >> 16)};
#pragma unroll
    for (int j = 0; j < 4; ++j)
      *(u16t*)((char*)cm + OFFSW(brow + j, hc2)) = ev[j];
  }
  __syncthreads();
  const int lane = tid & 63, w = tid >> 6;
  const int mt = w & 3, nbs = (w >> 2) * 4;
  const int arow = mt * 16 + (lane & 15);
  const int abase = arow * 512 + (lane >> 4) * 16;
  const int asw = (lane & 7) << 4;
  const f32x4 Z = {0.f, 0.f, 0.f, 0.f};
  f32x4 acc[4] = {Z, Z, Z, Z};
  const s16x8* wo = (const s16x8*)wpack + 6 * 8192;
#pragma unroll
  for (int ks = 0; ks < 8; ++ks) {
    s16x8 a = *(const s16x8*)((char*)cm + ((abase + ks * 64) ^ asw));
#pragma unroll
    for (int p = 0; p < 4; ++p)
      acc[p] = MF(a, wo[((nbs + p) * 8 + ks) * 64 + lane], acc[p]);
  }
#pragma unroll
  for (int p = 0; p < 4; ++p) {
    int col = (nbs + p) * 16 + (lane & 15);
    float bv = bout[col];
    size_t rb = (size_t)t * 256 + b0 + mt * 16 + (lane >> 4) * 4;
#pragma unroll
    for (int j = 0; j < 4; ++j)
      out[(rb + j) * 256 + col] = acc[p][j] + bv;
  }
}

extern "C" void kernel_launch(void* const* d_in, const int* in_sizes, int n_in,
                              void* d_out, int out_size, void* d_ws, size_t ws_size,
                              hipStream_t stream) {
  const float* x    = (const float*)d_in[0];
  const float* h0   = (const float*)d_in[1];
  const float* wxr  = (const float*)d_in[2];
  const float* whr  = (const float*)d_in[3];
  const float* br   = (const float*)d_in[4];
  const float* wxz  = (const float*)d_in[5];
  const float* whz  = (const float*)d_in[6];
  const float* bz   = (const float*)d_in[7];
  const float* wxh  = (const float*)d_in[8];
  const float* whh  = (const float*)d_in[9];
  const float* bh   = (const float*)d_in[10];
  const float* wout = (const float*)d_in[11];
  const float* bout = (const float*)d_in[12];

  float* out  = (float*)d_out;
  u16t* wpack = (u16t*)d_ws;                               // 896 KB
  u16t* xh_p  = (u16t*)((char*)d_ws + (1u << 20));         // 128 MB (cand in-place)
  u16t* xr_p  = (u16t*)d_out;                              // scratch in outs region
  u16t* xz_p  = (u16t*)((char*)d_out + GBYTES);            // scratch in outs region
  float* hout = (float*)((char*)d_out + 2 * GBYTES);       // h_final slot

  pack_w<<<1792, 256, 0, stream>>>(wxr, wxz, wxh, whr, whz, whh, wout, wpack);
  gru_xproj<<<4096, 512, 0, stream>>>(x, wpack, br, bz, bh, xr_p, xz_p, xh_p);
  gru_scan<<<16, 512, 0, stream>>>(h0, wpack, xr_p, xz_p, xh_p, xh_p, hout);
  gru_out<<<4096, 1024, 0, stream>>>(xh_p, wpack, bout, out);
}

// Round 8
// 2889.918 us; speedup vs baseline: 1.5879x; 1.5879x over previous
//
#include <hip/hip_runtime.h>

// GRU: T=1024, B=256, I=H=O=256, fp32 in/out, bf16 MFMA internally.
// d_out layout: outs [T*B][O] fp32 then h_final [B][H] fp32.
// xr_p/xz_p (bf16 packed, 134MB each) live in the d_out outs region and are
// fully consumed by gru_scan before gru_out overwrites it. xh_p lives in d_ws
// and is overwritten in-place by cand during the scan.
// R1: LDS-only barriers (no vmcnt drain).
// R2: VALU diet (v_rcp, v_cvt_pk_bf16_f32, MFMA C-in seeded with x-preacts).
// R4: whr+whh register/AGPR-resident (PINned); whz streamed via 2-deep dbuf.
// R5 (FAILED): paired-nb layout was the bug (proven by R6 passing).
// R6: log2e folding correct BUT s_setprio around MFMA clusters cost +80%
//     (stall +3900 cyc/step: lockstep 2-wave/SIMD starvation + sched fence).
// R7 = R6 minus ALL setprio (single-variable revert; keep folding).

typedef unsigned short u16t;
typedef unsigned int   u32t;
typedef short  s16x8 __attribute__((ext_vector_type(8)));
typedef float  f32x4 __attribute__((ext_vector_type(4)));
typedef float  f32v4 __attribute__((ext_vector_type(4)));
typedef u32t   u32x2 __attribute__((ext_vector_type(2)));

#define GBYTES 134217728ull   // T*B*H * 2 bytes (one packed gate)
#define L2E 1.4426950408889634f

// LDS-only barrier: order ds ops, leave vmcnt in flight.
#define BAR_LDS() asm volatile("s_waitcnt lgkmcnt(0)\n\ts_barrier" ::: "memory")
// Pin a value in VGPRs/AGPRs: opaque to the optimizer, no remat.
#define PIN(v) asm volatile("" : "+v"(v))

__device__ __forceinline__ float lo_f(u32t u) {
  return __builtin_bit_cast(float, u << 16);
}
__device__ __forceinline__ float hi_f(u32t u) {
  return __builtin_bit_cast(float, u & 0xffff0000u);
}
__device__ __forceinline__ u32t f2bf(float f) {  // round-to-nearest-even
  u32t u = __builtin_bit_cast(u32t, f);
  return (u + 0x7fffu + ((u >> 16) & 1u)) >> 16;
}
__device__ __forceinline__ u32t cvtpk(float lo, float hi) {  // 2xbf16 RNE pack
  u32t r;
  asm("v_cvt_pk_bf16_f32 %0, %1, %2" : "=v"(r) : "v"(lo), "v"(hi));
  return r;
}
__device__ __forceinline__ f32x4 MF(s16x8 a, s16x8 b, f32x4 c) {
  return __builtin_amdgcn_mfma_f32_16x16x32_bf16(a, b, c, 0, 0, 0);
}
// y = x*log2e already folded into operands: sigma(x) = 1/(1+2^-y)
__device__ __forceinline__ float sigm2(float y) {
  return __builtin_amdgcn_rcpf(1.0f + __builtin_amdgcn_exp2f(-y));
}
// y = x*2*log2e folded: tanh(x) = 1 - 2/(2^y + 1)
__device__ __forceinline__ float tanh2(float y) {
  return fmaf(-2.0f, __builtin_amdgcn_rcpf(__builtin_amdgcn_exp2f(y) + 1.0f), 1.0f);
}

// ---------------------------------------------------------------------------
// Pack 7 weight matrices [256x256] fp32 row-major -> bf16 MFMA-B fragments,
// pre-scaled: wxr,wxz,whr,whz by log2e; wxh,whh by 2*log2e; wout by 1.
// Fragment (nb, ks): lane holds W[ks*32 + (lane>>4)*8 + j][nb*16 + (lane&15)],
// stored at element ((nb*8+ks)*64 + lane)*8 + j.
// Order: [wxr, wxz, wxh, whr, whz, whh, wout] at 65536-elem strides.
// ---------------------------------------------------------------------------
__global__ void pack_w(const float* __restrict__ wxr, const float* __restrict__ wxz,
                       const float* __restrict__ wxh, const float* __restrict__ whr,
                       const float* __restrict__ whz, const float* __restrict__ whh,
                       const float* __restrict__ wout, u16t* __restrict__ dst) {
  int e = blockIdx.x * 256 + threadIdx.x;     // [0, 7*65536)
  int mat = e >> 16, i = e & 65535;
  const float* src = mat == 0 ? wxr : mat == 1 ? wxz : mat == 2 ? wxh
                   : mat == 3 ? whr : mat == 4 ? whz : mat == 5 ? whh : wout;
  float sc = (mat == 2 || mat == 5) ? 2.0f * L2E : (mat == 6 ? 1.0f : L2E);
  int j = i & 7, lane = (i >> 3) & 63, ks = (i >> 9) & 7, nb = i >> 12;
  int k = ks * 32 + (lane >> 4) * 8 + j;
  int n = nb * 16 + (lane & 15);
  dst[e] = (u16t)f2bf(src[k * 256 + n] * sc);
}

// ---------------------------------------------------------------------------
// Phase 1: xg = x @ Wxg + bg (pre-scaled), written bf16 in C-frag-packed
// layout: gate_p[((t*16+wg)*16+nb)*64+lane] (u32x2 = 4 bf16 regs).
// ---------------------------------------------------------------------------
__global__ __launch_bounds__(512, 2) void gru_xproj(
    const float* __restrict__ x, const u16t* __restrict__ wpack,
    const float* __restrict__ br, const float* __restrict__ bz,
    const float* __restrict__ bh,
    u16t* __restrict__ xr_p, u16t* __restrict__ xz_p, u16t* __restrict__ xh_p) {
  __shared__ __align__(128) u16t xt[16384];   // [64][256] bf16, XOR-swizzled
  const int tid = threadIdx.x, bid = blockIdx.x;
  const int t = bid >> 2, b0 = (bid & 3) * 64;
  const float* xrow = x + ((size_t)t * 256 + b0) * 256;
#pragma unroll
  for (int c = 0; c < 8; ++c) {
    int f4 = c * 512 + tid;                   // [0,4096) float4s
    f32v4 v = ((const f32v4*)xrow)[f4];
    u32t lo = f2bf(v[0]) | (f2bf(v[1]) << 16);
    u32t hi = f2bf(v[2]) | (f2bf(v[3]) << 16);
    int row = f4 >> 6, c8 = (f4 & 63) * 8;
    int off = (row * 512 + c8) ^ ((row & 7) << 4);
    u32x2 vv; vv[0] = lo; vv[1] = hi;
    *(u32x2*)((char*)xt + off) = vv;
  }
  __syncthreads();
  const int lane = tid & 63, w = tid >> 6;
  const int mt = w & 3, half = w >> 2;
  const int arow = mt * 16 + (lane & 15);
  const int abase = arow * 512 + (lane >> 4) * 16;
  const int asw = (lane & 7) << 4;
  const f32x4 Z = {0.f, 0.f, 0.f, 0.f};
  f32x4 acc[24];
#pragma unroll
  for (int p = 0; p < 24; ++p) acc[p] = Z;
#pragma unroll
  for (int ks = 0; ks < 8; ++ks) {
    s16x8 a = *(const s16x8*)((char*)xt + ((abase + ks * 64) ^ asw));
#pragma unroll
    for (int p = 0; p < 24; ++p) {
      int pj = half * 24 + p;
      int gate = pj >> 4, nb = pj & 15;
      const s16x8* wb = (const s16x8*)wpack + gate * 8192;
      acc[p] = MF(a, wb[(nb * 8 + ks) * 64 + lane], acc[p]);
    }
  }
  const int wg = (b0 >> 4) + mt;
#pragma unroll
  for (int p = 0; p < 24; ++p) {
    int pj = half * 24 + p;
    int gate = pj >> 4, nb = pj & 15;
    const float* bp = gate == 0 ? br : gate == 1 ? bz : bh;
    float bs = (gate == 2) ? 2.0f * L2E : L2E;
    float bv = bp[nb * 16 + (lane & 15)] * bs;
    u32t lo = f2bf(acc[p][0] + bv) | (f2bf(acc[p][1] + bv) << 16);
    u32t hi = f2bf(acc[p][2] + bv) | (f2bf(acc[p][3] + bv) << 16);
    u16t* op = gate == 0 ? xr_p : gate == 1 ? xz_p : xh_p;
    size_t off = (((size_t)t * 16 + wg) * 16 + nb) * 64 + lane;
    u32x2 vv; vv[0] = lo; vv[1] = hi;
    ((u32x2*)op)[off] = vv;
  }
}

// ---------------------------------------------------------------------------
// Phase 2: sequential scan. 16 WGs x 512 thr (8 waves; wave w owns cols
// [w*32, w*32+32) = nb {2w, 2w+1}). h fp32 in registers (C-frag layout);
// bf16 h / r*h through XOR-swizzled LDS as A-fragments.
// whr + whh AGPR-resident (pinned); whz streamed from L2 via dbuf.
// ---------------------------------------------------------------------------
#define OFFSW(row, colx2) (((row) * 512 + (colx2)) ^ (((row) & 7) << 4))
#define LDA_HB(ks) (*(const s16x8*)((char*)hb + ((aoff + (ks) * 64) ^ asw)))
#define LDA_RH(ks) (*(const s16x8*)((char*)rh + ((aoff + (ks) * 64) ^ asw)))
#define ZLOAD(buf, ks) do { buf[0] = pz[(ks) * 64]; buf[1] = pz[(ks) * 64 + 512]; } while (0)
#define G1_STEP(buf, ks) do { s16x8 a_ = LDA_HB(ks); \
    ar0 = MF(a_, whr_r[0][ks], ar0); ar1 = MF(a_, whr_r[1][ks], ar1); \
    az0 = MF(a_, buf[0], az0);       az1 = MF(a_, buf[1], az1); } while (0)

__global__ __launch_bounds__(512, 2) void gru_scan(
    const float* __restrict__ h0, const u16t* __restrict__ wpack,
    const u16t* __restrict__ xr_p, const u16t* __restrict__ xz_p,
    const u16t* __restrict__ xh_p, u16t* __restrict__ cand_p,
    float* __restrict__ hout) {
  __shared__ __align__(128) u16t hb[4096];    // [16][256] bf16 swizzled
  __shared__ __align__(128) u16t rh[4096];
  const int tid = threadIdx.x, lane = tid & 63, w = tid >> 6;
  const int wg = blockIdx.x;
  const int rlo = (lane >> 4) * 4;            // local row base (0,4,8,12)
  const int cA = w * 32 + (lane & 15);        // column for c=0 (c=1 -> +16)

  float hr_[2][4];
#pragma unroll
  for (int c = 0; c < 2; ++c)
#pragma unroll
    for (int j = 0; j < 4; ++j)
      hr_[c][j] = h0[(size_t)(wg * 16 + rlo + j) * 256 + cA + c * 16];
#pragma unroll
  for (int c = 0; c < 2; ++c)
#pragma unroll
    for (int j = 0; j < 4; ++j)
      *(u16t*)((char*)hb + OFFSW(rlo + j, (cA + c * 16) * 2)) = (u16t)f2bf(hr_[c][j]);
  __syncthreads();

  const s16x8* pz = (const s16x8*)wpack + 4 * 8192 + w * 1024 + lane;
  const int aoff = (lane & 15) * 512 + (lane >> 4) * 16;
  const int asw = (lane & 7) << 4;

  // whr / whh resident (pinned; allocator uses AGPRs, zero in-loop cost).
  s16x8 whr_r[2][8], whh_r[2][8];
  {
    const s16x8* prw = (const s16x8*)wpack + 3 * 8192;
    const s16x8* phw = (const s16x8*)wpack + 5 * 8192;
#pragma unroll
    for (int c = 0; c < 2; ++c)
#pragma unroll
      for (int ks = 0; ks < 8; ++ks) {
        int fo = ((2 * w + c) * 8 + ks) * 64 + lane;
        whr_r[c][ks] = prw[fo]; PIN(whr_r[c][ks]);
        whh_r[c][ks] = phw[fo]; PIN(whh_r[c][ks]);
      }
  }

  const size_t xoff = (size_t)(wg * 16 + 2 * w) * 64 + lane;  // u32x2 units
  const u32x2* PXR = (const u32x2*)xr_p;
  const u32x2* PXZ = (const u32x2*)xz_p;
  const u32x2* PXH = (const u32x2*)xh_p;
  u32x2* SXH = (u32x2*)cand_p;

  u32x2 vxr0 = PXR[xoff], vxr1 = PXR[xoff + 64];
  u32x2 vxz0 = PXZ[xoff], vxz1 = PXZ[xoff + 64];
  u32x2 vxh0 = PXH[xoff], vxh1 = PXH[xoff + 64];

  s16x8 bA[2], bB[2];
  ZLOAD(bA, 0);
  ZLOAD(bB, 1);

  for (int t = 0; t < 1024; ++t) {
    // G1: accs seeded with x-preacts; whz dbuf-streamed; whr from regs.
    f32x4 ar0, ar1, az0, az1;
    ar0[0] = lo_f(vxr0[0]); ar0[1] = hi_f(vxr0[0]); ar0[2] = lo_f(vxr0[1]); ar0[3] = hi_f(vxr0[1]);
    ar1[0] = lo_f(vxr1[0]); ar1[1] = hi_f(vxr1[0]); ar1[2] = lo_f(vxr1[1]); ar1[3] = hi_f(vxr1[1]);
    az0[0] = lo_f(vxz0[0]); az0[1] = hi_f(vxz0[0]); az0[2] = lo_f(vxz0[1]); az0[3] = hi_f(vxz0[1]);
    az1[0] = lo_f(vxz1[0]); az1[1] = hi_f(vxz1[0]); az1[2] = lo_f(vxz1[1]); az1[3] = hi_f(vxz1[1]);

    G1_STEP(bA, 0); ZLOAD(bA, 2);
    G1_STEP(bB, 1); ZLOAD(bB, 3);
    G1_STEP(bA, 2); ZLOAD(bA, 4);
    G1_STEP(bB, 3); ZLOAD(bB, 5);
    G1_STEP(bA, 4); ZLOAD(bA, 6);
    G1_STEP(bB, 5); ZLOAD(bB, 7);
    G1_STEP(bA, 6);
    G1_STEP(bB, 7);

    float r_[2][4];
    r_[0][0] = sigm2(ar0[0]); r_[0][1] = sigm2(ar0[1]); r_[0][2] = sigm2(ar0[2]); r_[0][3] = sigm2(ar0[3]);
    r_[1][0] = sigm2(ar1[0]); r_[1][1] = sigm2(ar1[1]); r_[1][2] = sigm2(ar1[2]); r_[1][3] = sigm2(ar1[3]);

#pragma unroll
    for (int c = 0; c < 2; ++c) {
      u32t p01 = cvtpk(r_[c][0] * hr_[c][0], r_[c][1] * hr_[c][1]);
      u32t p23 = cvtpk(r_[c][2] * hr_[c][2], r_[c][3] * hr_[c][3]);
      *(u16t*)((char*)rh + OFFSW(rlo + 0, (cA + c * 16) * 2)) = (u16t)p01;
      *(u16t*)((char*)rh + OFFSW(rlo + 1, (cA + c * 16) * 2)) = (u16t)(p01 >> 16);
      *(u16t*)((char*)rh + OFFSW(rlo + 2, (cA + c * 16) * 2)) = (u16t)p23;
      *(u16t*)((char*)rh + OFFSW(rlo + 3, (cA + c * 16) * 2)) = (u16t)(p23 >> 16);
    }
    BAR_LDS();

    // barrier shadow: z-sigmoid + G2 seeding + x reload for t+1
    float z_[2][4];
    z_[0][0] = sigm2(az0[0]); z_[0][1] = sigm2(az0[1]); z_[0][2] = sigm2(az0[2]); z_[0][3] = sigm2(az0[3]);
    z_[1][0] = sigm2(az1[0]); z_[1][1] = sigm2(az1[1]); z_[1][2] = sigm2(az1[2]); z_[1][3] = sigm2(az1[3]);

    f32x4 ac0, ac1;
    ac0[0] = lo_f(vxh0[0]); ac0[1] = hi_f(vxh0[0]); ac0[2] = lo_f(vxh0[1]); ac0[3] = hi_f(vxh0[1]);
    ac1[0] = lo_f(vxh1[0]); ac1[1] = hi_f(vxh1[0]); ac1[2] = lo_f(vxh1[1]); ac1[3] = hi_f(vxh1[1]);

    {  // reload x regs for t+1 (consumed above; arrival needed next step)
      size_t onext = xoff + (size_t)(t < 1023 ? t + 1 : t) * 16384;
      vxr0 = PXR[onext]; vxr1 = PXR[onext + 64];
      vxz0 = PXZ[onext]; vxz1 = PXZ[onext + 64];
      vxh0 = PXH[onext]; vxh1 = PXH[onext + 64];
    }

    // G2: (r.h) @ Whh with register-resident B
#pragma unroll
    for (int ks = 0; ks < 8; ++ks) {
      s16x8 a_ = LDA_RH(ks);
      ac0 = MF(a_, whh_r[0][ks], ac0);
      ac1 = MF(a_, whh_r[1][ks], ac1);
    }

    float cd[2][4];
    cd[0][0] = tanh2(ac0[0]); cd[0][1] = tanh2(ac0[1]); cd[0][2] = tanh2(ac0[2]); cd[0][3] = tanh2(ac0[3]);
    cd[1][0] = tanh2(ac1[0]); cd[1][1] = tanh2(ac1[1]); cd[1][2] = tanh2(ac1[2]); cd[1][3] = tanh2(ac1[3]);

    // store cand (bf16) over xh_p[t] via cand_p
    size_t ocur = xoff + (size_t)t * 16384;
    u32x2 s0, s1;
    s0[0] = cvtpk(cd[0][0], cd[0][1]); s0[1] = cvtpk(cd[0][2], cd[0][3]);
    s1[0] = cvtpk(cd[1][0], cd[1][1]); s1[1] = cvtpk(cd[1][2], cd[1][3]);
    SXH[ocur] = s0;
    SXH[ocur + 64] = s1;

    // h update + hb refresh
#pragma unroll
    for (int c = 0; c < 2; ++c) {
#pragma unroll
      for (int j = 0; j < 4; ++j)
        hr_[c][j] = fmaf(z_[c][j], hr_[c][j] - cd[c][j], cd[c][j]);
      u32t p01 = cvtpk(hr_[c][0], hr_[c][1]);
      u32t p23 = cvtpk(hr_[c][2], hr_[c][3]);
      *(u16t*)((char*)hb + OFFSW(rlo + 0, (cA + c * 16) * 2)) = (u16t)p01;
      *(u16t*)((char*)hb + OFFSW(rlo + 1, (cA + c * 16) * 2)) = (u16t)(p01 >> 16);
      *(u16t*)((char*)hb + OFFSW(rlo + 2, (cA + c * 16) * 2)) = (u16t)p23;
      *(u16t*)((char*)hb + OFFSW(rlo + 3, (cA + c * 16) * 2)) = (u16t)(p23 >> 16);
    }

    // cross-barrier preload of next step's first whz frags
    ZLOAD(bA, 0);
    ZLOAD(bB, 1);
    BAR_LDS();
  }
#pragma unroll
  for (int c = 0; c < 2; ++c)
#pragma unroll
    for (int j = 0; j < 4; ++j)
      hout[(size_t)(wg * 16 + rlo + j) * 256 + cA + c * 16] = hr_[c][j];
}

// ---------------------------------------------------------------------------
// Phase 3: outs = cand @ Wout + bout (fp32 out).
// ---------------------------------------------------------------------------
__global__ __launch_bounds__(1024, 4) void gru_out(
    const u16t* __restrict__ cand_p, const u16t* __restrict__ wpack,
    const float* __restrict__ bout, float* __restrict__ out) {
  __shared__ __align__(128) u16t cm[16384];   // [64][256] bf16 swizzled
  const int tid = threadIdx.x, bid = blockIdx.x;
  const int t = bid >> 2, q = bid & 3, b0 = q * 64;
  const u32x2* src = (const u32x2*)cand_p + ((size_t)t * 16 + q * 4) * 1024;
#pragma unroll
  for (int it = 0; it < 4; ++it) {
    int i = it * 1024 + tid;
    u32x2 v = src[i];
    int wg_l = i >> 10, nb = (i >> 6) & 15, ls = i & 63;
    int brow = wg_l * 16 + (ls >> 4) * 4;
    int hc2 = (nb * 16 + (ls & 15)) * 2;
    u16t ev[4] = {(u16t)(v[0] & 0xffff), (u16t)(v[0] >> 16),
                  (u16t)(v[1] & 0xffff), (u16t)(v[1] >> 16)};
#pragma unroll
    for (int j = 0; j < 4; ++j)
      *(u16t*)((char*)cm + OFFSW(brow + j, hc2)) = ev[j];
  }
  __syncthreads();
  const int lane = tid & 63, w = tid >> 6;
  const int mt = w & 3, nbs = (w >> 2) * 4;
  const int arow = mt * 16 + (lane & 15);
  const int abase = arow * 512 + (lane >> 4) * 16;
  const int asw = (lane & 7) << 4;
  const f32x4 Z = {0.f, 0.f, 0.f, 0.f};
  f32x4 acc[4] = {Z, Z, Z, Z};
  const s16x8* wo = (const s16x8*)wpack + 6 * 8192;
#pragma unroll
  for (int ks = 0; ks < 8; ++ks) {
    s16x8 a = *(const s16x8*)((char*)cm + ((abase + ks * 64) ^ asw));
#pragma unroll
    for (int p = 0; p < 4; ++p)
      acc[p] = MF(a, wo[((nbs + p) * 8 + ks) * 64 + lane], acc[p]);
  }
#pragma unroll
  for (int p = 0; p < 4; ++p) {
    int col = (nbs + p) * 16 + (lane & 15);
    float bv = bout[col];
    size_t rb = (size_t)t * 256 + b0 + mt * 16 + (lane >> 4) * 4;
#pragma unroll
    for (int j = 0; j < 4; ++j)
      out[(rb + j) * 256 + col] = acc[p][j] + bv;
  }
}

extern "C" void kernel_launch(void* const* d_in, const int* in_sizes, int n_in,
                              void* d_out, int out_size, void* d_ws, size_t ws_size,
                              hipStream_t stream) {
  const float* x    = (const float*)d_in[0];
  const float* h0   = (const float*)d_in[1];
  const float* wxr  = (const float*)d_in[2];
  const float* whr  = (const float*)d_in[3];
  const float* br   = (const float*)d_in[4];
  const float* wxz  = (const float*)d_in[5];
  const float* whz  = (const float*)d_in[6];
  const float* bz   = (const float*)d_in[7];
  const float* wxh  = (const float*)d_in[8];
  const float* whh  = (const float*)d_in[9];
  const float* bh   = (const float*)d_in[10];
  const float* wout = (const float*)d_in[11];
  const float* bout = (const float*)d_in[12];

  float* out  = (float*)d_out;
  u16t* wpack = (u16t*)d_ws;                               // 896 KB
  u16t* xh_p  = (u16t*)((char*)d_ws + (1u << 20));         // 128 MB (cand in-place)
  u16t* xr_p  = (u16t*)d_out;                              // scratch in outs region
  u16t* xz_p  = (u16t*)((char*)d_out + GBYTES);            // scratch in outs region
  float* hout = (float*)((char*)d_out + 2 * GBYTES);       // h_final slot

  pack_w<<<1792, 256, 0, stream>>>(wxr, wxz, wxh, whr, whz, whh, wout, wpack);
  gru_xproj<<<4096, 512, 0, stream>>>(x, wpack, br, bz, bh, xr_p, xz_p, xh_p);
  gru_scan<<<16, 512, 0, stream>>>(h0, wpack, xr_p, xz_p, xh_p, xh_p, hout);
  gru_out<<<4096, 1024, 0, stream>>>(xh_p, wpack, bout, out);
}

// Round 9
// 2622.044 us; speedup vs baseline: 1.7501x; 1.1022x over previous
//
#include <hip/hip_runtime.h>

// GRU: T=1024, B=256, I=H=O=256, fp32 in/out, bf16 MFMA internally.
// d_out layout: outs [T*B][O] fp32 then h_final [B][H] fp32.
// xr_p/xz_p (bf16 packed, 134MB each) live in the d_out outs region and are
// fully consumed by gru_scan before gru_out overwrites it. xh_p lives in d_ws
// and is overwritten in-place by cand during the scan.
// R1: LDS-only barriers (no vmcnt drain).
// R2: VALU diet (v_rcp, v_cvt_pk_bf16_f32, MFMA C-in seeded with x-preacts).
// R4: whr+whh register/AGPR-resident (PINned); whz streamed via 2-deep dbuf.
// R6: log2e folding (kept); s_setprio (REVERTED in R7: +80% on lockstep).
// R7: baseline 2890us = scan 2035 + others 855.
// R8: gru_xproj restructured for B-reuse: M=32 rows/wave (2 A-sets share
//     every B-frag), 12 (gate,nb) combos/wave -> per-wave B-frag L2 traffic
//     halves (192KB->96KB), total 6.1GB->3.1GB. Scan untouched.

typedef unsigned short u16t;
typedef unsigned int   u32t;
typedef short  s16x8 __attribute__((ext_vector_type(8)));
typedef float  f32x4 __attribute__((ext_vector_type(4)));
typedef float  f32v4 __attribute__((ext_vector_type(4)));
typedef u32t   u32x2 __attribute__((ext_vector_type(2)));

#define GBYTES 134217728ull   // T*B*H * 2 bytes (one packed gate)
#define L2E 1.4426950408889634f

// LDS-only barrier: order ds ops, leave vmcnt in flight.
#define BAR_LDS() asm volatile("s_waitcnt lgkmcnt(0)\n\ts_barrier" ::: "memory")
// Pin a value in VGPRs/AGPRs: opaque to the optimizer, no remat.
#define PIN(v) asm volatile("" : "+v"(v))

__device__ __forceinline__ float lo_f(u32t u) {
  return __builtin_bit_cast(float, u << 16);
}
__device__ __forceinline__ float hi_f(u32t u) {
  return __builtin_bit_cast(float, u & 0xffff0000u);
}
__device__ __forceinline__ u32t f2bf(float f) {  // round-to-nearest-even
  u32t u = __builtin_bit_cast(u32t, f);
  return (u + 0x7fffu + ((u >> 16) & 1u)) >> 16;
}
__device__ __forceinline__ u32t cvtpk(float lo, float hi) {  // 2xbf16 RNE pack
  u32t r;
  asm("v_cvt_pk_bf16_f32 %0, %1, %2" : "=v"(r) : "v"(lo), "v"(hi));
  return r;
}
__device__ __forceinline__ f32x4 MF(s16x8 a, s16x8 b, f32x4 c) {
  return __builtin_amdgcn_mfma_f32_16x16x32_bf16(a, b, c, 0, 0, 0);
}
// y = x*log2e already folded into operands: sigma(x) = 1/(1+2^-y)
__device__ __forceinline__ float sigm2(float y) {
  return __builtin_amdgcn_rcpf(1.0f + __builtin_amdgcn_exp2f(-y));
}
// y = x*2*log2e folded: tanh(x) = 1 - 2/(2^y + 1)
__device__ __forceinline__ float tanh2(float y) {
  return fmaf(-2.0f, __builtin_amdgcn_rcpf(__builtin_amdgcn_exp2f(y) + 1.0f), 1.0f);
}

// ---------------------------------------------------------------------------
// Pack 7 weight matrices [256x256] fp32 row-major -> bf16 MFMA-B fragments,
// pre-scaled: wxr,wxz,whr,whz by log2e; wxh,whh by 2*log2e; wout by 1.
// Fragment (nb, ks): lane holds W[ks*32 + (lane>>4)*8 + j][nb*16 + (lane&15)],
// stored at element ((nb*8+ks)*64 + lane)*8 + j.
// Order: [wxr, wxz, wxh, whr, whz, whh, wout] at 65536-elem strides.
// ---------------------------------------------------------------------------
__global__ void pack_w(const float* __restrict__ wxr, const float* __restrict__ wxz,
                       const float* __restrict__ wxh, const float* __restrict__ whr,
                       const float* __restrict__ whz, const float* __restrict__ whh,
                       const float* __restrict__ wout, u16t* __restrict__ dst) {
  int e = blockIdx.x * 256 + threadIdx.x;     // [0, 7*65536)
  int mat = e >> 16, i = e & 65535;
  const float* src = mat == 0 ? wxr : mat == 1 ? wxz : mat == 2 ? wxh
                   : mat == 3 ? whr : mat == 4 ? whz : mat == 5 ? whh : wout;
  float sc = (mat == 2 || mat == 5) ? 2.0f * L2E : (mat == 6 ? 1.0f : L2E);
  int j = i & 7, lane = (i >> 3) & 63, ks = (i >> 9) & 7, nb = i >> 12;
  int k = ks * 32 + (lane >> 4) * 8 + j;
  int n = nb * 16 + (lane & 15);
  dst[e] = (u16t)f2bf(src[k * 256 + n] * sc);
}

// ---------------------------------------------------------------------------
// Phase 1: xg = x @ Wxg + bg (pre-scaled), written bf16 in C-frag-packed
// layout: gate_p[((t*16+wg)*16+nb)*64+lane] (u32x2 = 4 bf16 regs).
// R8: wave w handles M=32 rows (m2=w&1 -> rows m2*32 + s*16, s=0,1) and 12
// (gate,nb) combos (cg=w>>1). Both A-sets share each B-frag -> L2 B-traffic
// per wave halves (96KB vs 192KB).
// ---------------------------------------------------------------------------
__global__ __launch_bounds__(512, 2) void gru_xproj(
    const float* __restrict__ x, const u16t* __restrict__ wpack,
    const float* __restrict__ br, const float* __restrict__ bz,
    const float* __restrict__ bh,
    u16t* __restrict__ xr_p, u16t* __restrict__ xz_p, u16t* __restrict__ xh_p) {
  __shared__ __align__(128) u16t xt[16384];   // [64][256] bf16, XOR-swizzled
  const int tid = threadIdx.x, bid = blockIdx.x;
  const int t = bid >> 2, b0 = (bid & 3) * 64;
  const float* xrow = x + ((size_t)t * 256 + b0) * 256;
#pragma unroll
  for (int c = 0; c < 8; ++c) {
    int f4 = c * 512 + tid;                   // [0,4096) float4s
    f32v4 v = ((const f32v4*)xrow)[f4];
    u32t lo = f2bf(v[0]) | (f2bf(v[1]) << 16);
    u32t hi = f2bf(v[2]) | (f2bf(v[3]) << 16);
    int row = f4 >> 6, c8 = (f4 & 63) * 8;
    int off = (row * 512 + c8) ^ ((row & 7) << 4);
    u32x2 vv; vv[0] = lo; vv[1] = hi;
    *(u32x2*)((char*)xt + off) = vv;
  }
  __syncthreads();
  const int lane = tid & 63, w = tid >> 6;
  const int m2 = w & 1, cg = w >> 1;          // rows m2*32+..; combos cg*12+..
  const int arow = m2 * 32 + (lane & 15);     // s=0 row; s=1 -> +16
  const int abase = arow * 512 + (lane >> 4) * 16;
  const int asw = (lane & 7) << 4;
  const f32x4 Z = {0.f, 0.f, 0.f, 0.f};
  f32x4 acc[2][12];
#pragma unroll
  for (int s = 0; s < 2; ++s)
#pragma unroll
    for (int p = 0; p < 12; ++p) acc[s][p] = Z;
#pragma unroll
  for (int ks = 0; ks < 8; ++ks) {
    s16x8 a0 = *(const s16x8*)((char*)xt + ((abase + ks * 64) ^ asw));
    s16x8 a1 = *(const s16x8*)((char*)xt + ((abase + 16 * 512 + ks * 64) ^ asw));
#pragma unroll
    for (int p = 0; p < 12; ++p) {
      int pj = cg * 12 + p;
      int gate = pj >> 4, nb = pj & 15;
      const s16x8* wb = (const s16x8*)wpack + gate * 8192;
      s16x8 b = wb[(nb * 8 + ks) * 64 + lane];
      acc[0][p] = MF(a0, b, acc[0][p]);
      acc[1][p] = MF(a1, b, acc[1][p]);
    }
  }
#pragma unroll
  for (int p = 0; p < 12; ++p) {
    int pj = cg * 12 + p;
    int gate = pj >> 4, nb = pj & 15;
    const float* bp = gate == 0 ? br : gate == 1 ? bz : bh;
    float bs = (gate == 2) ? 2.0f * L2E : L2E;
    float bv = bp[nb * 16 + (lane & 15)] * bs;
    u16t* op = gate == 0 ? xr_p : gate == 1 ? xz_p : xh_p;
#pragma unroll
    for (int s = 0; s < 2; ++s) {
      int wg = (b0 >> 4) + m2 * 2 + s;
      u32t lo = f2bf(acc[s][p][0] + bv) | (f2bf(acc[s][p][1] + bv) << 16);
      u32t hi = f2bf(acc[s][p][2] + bv) | (f2bf(acc[s][p][3] + bv) << 16);
      size_t off = (((size_t)t * 16 + wg) * 16 + nb) * 64 + lane;
      u32x2 vv; vv[0] = lo; vv[1] = hi;
      ((u32x2*)op)[off] = vv;
    }
  }
}

// ---------------------------------------------------------------------------
// Phase 2: sequential scan. 16 WGs x 512 thr (8 waves; wave w owns cols
// [w*32, w*32+32) = nb {2w, 2w+1}). h fp32 in registers (C-frag layout);
// bf16 h / r*h through XOR-swizzled LDS as A-fragments.
// whr + whh AGPR-resident (pinned); whz streamed from L2 via dbuf.
// ---------------------------------------------------------------------------
#define OFFSW(row, colx2) (((row) * 512 + (colx2)) ^ (((row) & 7) << 4))
#define LDA_HB(ks) (*(const s16x8*)((char*)hb + ((aoff + (ks) * 64) ^ asw)))
#define LDA_RH(ks) (*(const s16x8*)((char*)rh + ((aoff + (ks) * 64) ^ asw)))
#define ZLOAD(buf, ks) do { buf[0] = pz[(ks) * 64]; buf[1] = pz[(ks) * 64 + 512]; } while (0)
#define G1_STEP(buf, ks) do { s16x8 a_ = LDA_HB(ks); \
    ar0 = MF(a_, whr_r[0][ks], ar0); ar1 = MF(a_, whr_r[1][ks], ar1); \
    az0 = MF(a_, buf[0], az0);       az1 = MF(a_, buf[1], az1); } while (0)

__global__ __launch_bounds__(512, 2) void gru_scan(
    const float* __restrict__ h0, const u16t* __restrict__ wpack,
    const u16t* __restrict__ xr_p, const u16t* __restrict__ xz_p,
    const u16t* __restrict__ xh_p, u16t* __restrict__ cand_p,
    float* __restrict__ hout) {
  __shared__ __align__(128) u16t hb[4096];    // [16][256] bf16 swizzled
  __shared__ __align__(128) u16t rh[4096];
  const int tid = threadIdx.x, lane = tid & 63, w = tid >> 6;
  const int wg = blockIdx.x;
  const int rlo = (lane >> 4) * 4;            // local row base (0,4,8,12)
  const int cA = w * 32 + (lane & 15);        // column for c=0 (c=1 -> +16)

  float hr_[2][4];
#pragma unroll
  for (int c = 0; c < 2; ++c)
#pragma unroll
    for (int j = 0; j < 4; ++j)
      hr_[c][j] = h0[(size_t)(wg * 16 + rlo + j) * 256 + cA + c * 16];
#pragma unroll
  for (int c = 0; c < 2; ++c)
#pragma unroll
    for (int j = 0; j < 4; ++j)
      *(u16t*)((char*)hb + OFFSW(rlo + j, (cA + c * 16) * 2)) = (u16t)f2bf(hr_[c][j]);
  __syncthreads();

  const s16x8* pz = (const s16x8*)wpack + 4 * 8192 + w * 1024 + lane;
  const int aoff = (lane & 15) * 512 + (lane >> 4) * 16;
  const int asw = (lane & 7) << 4;

  // whr / whh resident (pinned; allocator uses AGPRs, zero in-loop cost).
  s16x8 whr_r[2][8], whh_r[2][8];
  {
    const s16x8* prw = (const s16x8*)wpack + 3 * 8192;
    const s16x8* phw = (const s16x8*)wpack + 5 * 8192;
#pragma unroll
    for (int c = 0; c < 2; ++c)
#pragma unroll
      for (int ks = 0; ks < 8; ++ks) {
        int fo = ((2 * w + c) * 8 + ks) * 64 + lane;
        whr_r[c][ks] = prw[fo]; PIN(whr_r[c][ks]);
        whh_r[c][ks] = phw[fo]; PIN(whh_r[c][ks]);
      }
  }

  const size_t xoff = (size_t)(wg * 16 + 2 * w) * 64 + lane;  // u32x2 units
  const u32x2* PXR = (const u32x2*)xr_p;
  const u32x2* PXZ = (const u32x2*)xz_p;
  const u32x2* PXH = (const u32x2*)xh_p;
  u32x2* SXH = (u32x2*)cand_p;

  u32x2 vxr0 = PXR[xoff], vxr1 = PXR[xoff + 64];
  u32x2 vxz0 = PXZ[xoff], vxz1 = PXZ[xoff + 64];
  u32x2 vxh0 = PXH[xoff], vxh1 = PXH[xoff + 64];

  s16x8 bA[2], bB[2];
  ZLOAD(bA, 0);
  ZLOAD(bB, 1);

  for (int t = 0; t < 1024; ++t) {
    // G1: accs seeded with x-preacts; whz dbuf-streamed; whr from regs.
    f32x4 ar0, ar1, az0, az1;
    ar0[0] = lo_f(vxr0[0]); ar0[1] = hi_f(vxr0[0]); ar0[2] = lo_f(vxr0[1]); ar0[3] = hi_f(vxr0[1]);
    ar1[0] = lo_f(vxr1[0]); ar1[1] = hi_f(vxr1[0]); ar1[2] = lo_f(vxr1[1]); ar1[3] = hi_f(vxr1[1]);
    az0[0] = lo_f(vxz0[0]); az0[1] = hi_f(vxz0[0]); az0[2] = lo_f(vxz0[1]); az0[3] = hi_f(vxz0[1]);
    az1[0] = lo_f(vxz1[0]); az1[1] = hi_f(vxz1[0]); az1[2] = lo_f(vxz1[1]); az1[3] = hi_f(vxz1[1]);

    G1_STEP(bA, 0); ZLOAD(bA, 2);
    G1_STEP(bB, 1); ZLOAD(bB, 3);
    G1_STEP(bA, 2); ZLOAD(bA, 4);
    G1_STEP(bB, 3); ZLOAD(bB, 5);
    G1_STEP(bA, 4); ZLOAD(bA, 6);
    G1_STEP(bB, 5); ZLOAD(bB, 7);
    G1_STEP(bA, 6);
    G1_STEP(bB, 7);

    float r_[2][4];
    r_[0][0] = sigm2(ar0[0]); r_[0][1] = sigm2(ar0[1]); r_[0][2] = sigm2(ar0[2]); r_[0][3] = sigm2(ar0[3]);
    r_[1][0] = sigm2(ar1[0]); r_[1][1] = sigm2(ar1[1]); r_[1][2] = sigm2(ar1[2]); r_[1][3] = sigm2(ar1[3]);

#pragma unroll
    for (int c = 0; c < 2; ++c) {
      u32t p01 = cvtpk(r_[c][0] * hr_[c][0], r_[c][1] * hr_[c][1]);
      u32t p23 = cvtpk(r_[c][2] * hr_[c][2], r_[c][3] * hr_[c][3]);
      *(u16t*)((char*)rh + OFFSW(rlo + 0, (cA + c * 16) * 2)) = (u16t)p01;
      *(u16t*)((char*)rh + OFFSW(rlo + 1, (cA + c * 16) * 2)) = (u16t)(p01 >> 16);
      *(u16t*)((char*)rh + OFFSW(rlo + 2, (cA + c * 16) * 2)) = (u16t)p23;
      *(u16t*)((char*)rh + OFFSW(rlo + 3, (cA + c * 16) * 2)) = (u16t)(p23 >> 16);
    }
    BAR_LDS();

    // barrier shadow: z-sigmoid + G2 seeding + x reload for t+1
    float z_[2][4];
    z_[0][0] = sigm2(az0[0]); z_[0][1] = sigm2(az0[1]); z_[0][2] = sigm2(az0[2]); z_[0][3] = sigm2(az0[3]);
    z_[1][0] = sigm2(az1[0]); z_[1][1] = sigm2(az1[1]); z_[1][2] = sigm2(az1[2]); z_[1][3] = sigm2(az1[3]);

    f32x4 ac0, ac1;
    ac0[0] = lo_f(vxh0[0]); ac0[1] = hi_f(vxh0[0]); ac0[2] = lo_f(vxh0[1]); ac0[3] = hi_f(vxh0[1]);
    ac1[0] = lo_f(vxh1[0]); ac1[1] = hi_f(vxh1[0]); ac1[2] = lo_f(vxh1[1]); ac1[3] = hi_f(vxh1[1]);

    {  // reload x regs for t+1 (consumed above; arrival needed next step)
      size_t onext = xoff + (size_t)(t < 1023 ? t + 1 : t) * 16384;
      vxr0 = PXR[onext]; vxr1 = PXR[onext + 64];
      vxz0 = PXZ[onext]; vxz1 = PXZ[onext + 64];
      vxh0 = PXH[onext]; vxh1 = PXH[onext + 64];
    }

    // G2: (r.h) @ Whh with register-resident B
#pragma unroll
    for (int ks = 0; ks < 8; ++ks) {
      s16x8 a_ = LDA_RH(ks);
      ac0 = MF(a_, whh_r[0][ks], ac0);
      ac1 = MF(a_, whh_r[1][ks], ac1);
    }

    float cd[2][4];
    cd[0][0] = tanh2(ac0[0]); cd[0][1] = tanh2(ac0[1]); cd[0][2] = tanh2(ac0[2]); cd[0][3] = tanh2(ac0[3]);
    cd[1][0] = tanh2(ac1[0]); cd[1][1] = tanh2(ac1[1]); cd[1][2] = tanh2(ac1[2]); cd[1][3] = tanh2(ac1[3]);

    // store cand (bf16) over xh_p[t] via cand_p
    size_t ocur = xoff + (size_t)t * 16384;
    u32x2 s0, s1;
    s0[0] = cvtpk(cd[0][0], cd[0][1]); s0[1] = cvtpk(cd[0][2], cd[0][3]);
    s1[0] = cvtpk(cd[1][0], cd[1][1]); s1[1] = cvtpk(cd[1][2], cd[1][3]);
    SXH[ocur] = s0;
    SXH[ocur + 64] = s1;

    // h update + hb refresh
#pragma unroll
    for (int c = 0; c < 2; ++c) {
#pragma unroll
      for (int j = 0; j < 4; ++j)
        hr_[c][j] = fmaf(z_[c][j], hr_[c][j] - cd[c][j], cd[c][j]);
      u32t p01 = cvtpk(hr_[c][0], hr_[c][1]);
      u32t p23 = cvtpk(hr_[c][2], hr_[c][3]);
      *(u16t*)((char*)hb + OFFSW(rlo + 0, (cA + c * 16) * 2)) = (u16t)p01;
      *(u16t*)((char*)hb + OFFSW(rlo + 1, (cA + c * 16) * 2)) = (u16t)(p01 >> 16);
      *(u16t*)((char*)hb + OFFSW(rlo + 2, (cA + c * 16) * 2)) = (u16t)p23;
      *(u16t*)((char*)hb + OFFSW(rlo + 3, (cA + c * 16) * 2)) = (u16t)(p23 >> 16);
    }

    // cross-barrier preload of next step's first whz frags
    ZLOAD(bA, 0);
    ZLOAD(bB, 1);
    BAR_LDS();
  }
#pragma unroll
  for (int c = 0; c < 2; ++c)
#pragma unroll
    for (int j = 0; j < 4; ++j)
      hout[(size_t)(wg * 16 + rlo + j) * 256 + cA + c * 16] = hr_[c][j];
}

// ---------------------------------------------------------------------------
// Phase 3: outs = cand @ Wout + bout (fp32 out).
// ---------------------------------------------------------------------------
__global__ __launch_bounds__(1024, 4) void gru_out(
    const u16t* __restrict__ cand_p, const u16t* __restrict__ wpack,
    const float* __restrict__ bout, float* __restrict__ out) {
  __shared__ __align__(128) u16t cm[16384];   // [64][256] bf16 swizzled
  const int tid = threadIdx.x, bid = blockIdx.x;
  const int t = bid >> 2, q = bid & 3, b0 = q * 64;
  const u32x2* src = (const u32x2*)cand_p + ((size_t)t * 16 + q * 4) * 1024;
#pragma unroll
  for (int it = 0; it < 4; ++it) {
    int i = it * 1024 + tid;
    u32x2 v = src[i];
    int wg_l = i >> 10, nb = (i >> 6) & 15, ls = i & 63;
    int brow = wg_l * 16 + (ls >> 4) * 4;
    int hc2 = (nb * 16 + (ls & 15)) * 2;
    u16t ev[4] = {(u16t)(v[0] & 0xffff), (u16t)(v[0] >> 16),
                  (u16t)(v[1] & 0xffff), (u16t)(v[1] >> 16)};
#pragma unroll
    for (int j = 0; j < 4; ++j)
      *(u16t*)((char*)cm + OFFSW(brow + j, hc2)) = ev[j];
  }
  __syncthreads();
  const int lane = tid & 63, w = tid >> 6;
  const int mt = w & 3, nbs = (w >> 2) * 4;
  const int arow = mt * 16 + (lane & 15);
  const int abase = arow * 512 + (lane >> 4) * 16;
  const int asw = (lane & 7) << 4;
  const f32x4 Z = {0.f, 0.f, 0.f, 0.f};
  f32x4 acc[4] = {Z, Z, Z, Z};
  const s16x8* wo = (const s16x8*)wpack + 6 * 8192;
#pragma unroll
  for (int ks = 0; ks < 8; ++ks) {
    s16x8 a = *(const s16x8*)((char*)cm + ((abase + ks * 64) ^ asw));
#pragma unroll
    for (int p = 0; p < 4; ++p)
      acc[p] = MF(a, wo[((nbs + p) * 8 + ks) * 64 + lane], acc[p]);
  }
#pragma unroll
  for (int p = 0; p < 4; ++p) {
    int col = (nbs + p) * 16 + (lane & 15);
    float bv = bout[col];
    size_t rb = (size_t)t * 256 + b0 + mt * 16 + (lane >> 4) * 4;
#pragma unroll
    for (int j = 0; j < 4; ++j)
      out[(rb + j) * 256 + col] = acc[p][j] + bv;
  }
}

extern "C" void kernel_launch(void* const* d_in, const int* in_sizes, int n_in,
                              void* d_out, int out_size, void* d_ws, size_t ws_size,
                              hipStream_t stream) {
  const float* x    = (const float*)d_in[0];
  const float* h0   = (const float*)d_in[1];
  const float* wxr  = (const float*)d_in[2];
  const float* whr  = (const float*)d_in[3];
  const float* br   = (const float*)d_in[4];
  const float* wxz  = (const float*)d_in[5];
  const float* whz  = (const float*)d_in[6];
  const float* bz   = (const float*)d_in[7];
  const float* wxh  = (const float*)d_in[8];
  const float* whh  = (const float*)d_in[9];
  const float* bh   = (const float*)d_in[10];
  const float* wout = (const float*)d_in[11];
  const float* bout = (const float*)d_in[12];

  float* out  = (float*)d_out;
  u16t* wpack = (u16t*)d_ws;                               // 896 KB
  u16t* xh_p  = (u16t*)((char*)d_ws + (1u << 20));         // 128 MB (cand in-place)
  u16t* xr_p  = (u16t*)d_out;                              // scratch in outs region
  u16t* xz_p  = (u16t*)((char*)d_out + GBYTES);            // scratch in outs region
  float* hout = (float*)((char*)d_out + 2 * GBYTES);       // h_final slot

  pack_w<<<1792, 256, 0, stream>>>(wxr, wxz, wxh, whr, whz, whh, wout, wpack);
  gru_xproj<<<4096, 512, 0, stream>>>(x, wpack, br, bz, bh, xr_p, xz_p, xh_p);
  gru_scan<<<16, 512, 0, stream>>>(h0, wpack, xr_p, xz_p, xh_p, xh_p, hout);
  gru_out<<<4096, 1024, 0, stream>>>(xh_p, wpack, bout, out);
}